// Round 1
// baseline (1225.622 us; speedup 1.0000x reference)
//
#include <hip/hip_runtime.h>

typedef unsigned short u16;
typedef unsigned int u32;
typedef __bf16 bf16x8 __attribute__((ext_vector_type(8)));
typedef float f32x4 __attribute__((ext_vector_type(4)));

#define N_NODES 10000
#define N_EDGES 160000
#define D_IN 512
#define D_HID 1024

__device__ __forceinline__ u16 f2bf(float f) {
    union { float f; u32 u; } v; v.f = f;
    return (u16)((v.u + 0x7fffu + ((v.u >> 16) & 1u)) >> 16);
}

// rst = (1 + eps) * feat
__global__ void init_rst_k(const float* __restrict__ feat, const float* __restrict__ eps,
                           float* __restrict__ rst, int n) {
    int i = (blockIdx.x * 256 + threadIdx.x) * 4;
    if (i >= n) return;
    float s = 1.0f + eps[0];
    float4 v = *(const float4*)(feat + i);
    v.x *= s; v.y *= s; v.z *= s; v.w *= s;
    *(float4*)(rst + i) = v;
}

// rst[dst] += feat[src] over all edges; 128 threads per edge, 4 floats/thread
__global__ void scatter_k(const float* __restrict__ feat, const int* __restrict__ src,
                          const int* __restrict__ dst, float* __restrict__ rst) {
    int gid = blockIdx.x * 256 + threadIdx.x;
    int e = gid >> 7;
    int lane = gid & 127;
    int s = src[e];
    int d = dst[e];
    float4 v = *(const float4*)(feat + (size_t)s * D_IN + lane * 4);
    float* p = rst + (size_t)d * D_IN + lane * 4;
    atomicAdd(p + 0, v.x);
    atomicAdd(p + 1, v.y);
    atomicAdd(p + 2, v.z);
    atomicAdd(p + 3, v.w);
}

// fp32 -> bf16 (RNE), 8 elems/thread
__global__ void cvt_bf16_k(const float* __restrict__ in, u16* __restrict__ out, int n) {
    int i = (blockIdx.x * 256 + threadIdx.x) * 8;
    if (i >= n) return;
    float4 a = *(const float4*)(in + i);
    float4 b = *(const float4*)(in + i + 4);
    uint4 o;
    o.x = (u32)f2bf(a.x) | ((u32)f2bf(a.y) << 16);
    o.y = (u32)f2bf(a.z) | ((u32)f2bf(a.w) << 16);
    o.z = (u32)f2bf(b.x) | ((u32)f2bf(b.y) << 16);
    o.w = (u32)f2bf(b.z) | ((u32)f2bf(b.w) << 16);
    *(uint4*)(out + i) = o;
}

// WT[n][k] = bf16(W[k][n]); W is K x N row-major. 32x32 tile via LDS.
__global__ void transpose_cvt_k(const float* __restrict__ W, u16* __restrict__ WT,
                                int K, int N) {
    __shared__ float tile[32][33];
    int n0 = blockIdx.x * 32, k0 = blockIdx.y * 32;
    int tx = threadIdx.x, ty = threadIdx.y;
#pragma unroll
    for (int i = 0; i < 32; i += 8)
        tile[ty + i][tx] = W[(size_t)(k0 + ty + i) * N + n0 + tx];
    __syncthreads();
#pragma unroll
    for (int i = 0; i < 32; i += 8)
        WT[(size_t)(n0 + ty + i) * K + k0 + tx] = f2bf(tile[tx][ty + i]);
}

// C[M,N] = A[M,K] @ B[K,N], A row-major bf16, BT = B^T row-major bf16 [N,K].
// 128x128 tile, BK=64, 256 threads (4 waves 2x2, 64x64 each), 16x16x32 bf16 MFMA.
// EPI=0: C = bf16(relu(acc + bias))      (Cout = u16*)
// EPI=1: C = acc + bias + feat (fp32)    (Cout = float*)
#define LDSP 72  // 64 + 8 pad: breaks the 16-way bank conflict, keeps 16B align
template <int EPI>
__global__ __launch_bounds__(256) void gemm_k(const u16* __restrict__ A,
                                              const u16* __restrict__ BT,
                                              const float* __restrict__ bias,
                                              const float* __restrict__ feat,
                                              void* __restrict__ Cout,
                                              int M, int N, int K) {
    __shared__ __bf16 sA[128 * LDSP];
    __shared__ __bf16 sB[128 * LDSP];
    const int row0 = blockIdx.y * 128;
    const int col0 = blockIdx.x * 128;
    const int t = threadIdx.x;
    const int w = t >> 6, l = t & 63;
    const int wm = (w >> 1) * 64, wn = (w & 1) * 64;
    const int lr = l & 15;   // row (A) / col (B) within 16-tile
    const int lq = l >> 4;   // k-quad

    f32x4 acc[4][4] = {};

    for (int k0 = 0; k0 < K; k0 += 64) {
        __syncthreads();
#pragma unroll
        for (int c = 0; c < 4; c++) {
            int eo = (c * 256 + t) * 8;      // 0..8191, 8-elem chunks
            int m = eo >> 6;
            int kk = eo & 63;
            int ar = row0 + m; if (ar >= M) ar = M - 1;
            *(uint4*)(&sA[m * LDSP + kk]) = *(const uint4*)(A + (size_t)ar * K + k0 + kk);
            int br = col0 + m;               // N is a multiple of 128
            *(uint4*)(&sB[m * LDSP + kk]) = *(const uint4*)(BT + (size_t)br * K + k0 + kk);
        }
        __syncthreads();
#pragma unroll
        for (int kk = 0; kk < 64; kk += 32) {
            bf16x8 fa[4], fb[4];
#pragma unroll
            for (int i = 0; i < 4; i++)
                fa[i] = *(const bf16x8*)(&sA[(wm + i * 16 + lr) * LDSP + kk + lq * 8]);
#pragma unroll
            for (int j = 0; j < 4; j++)
                fb[j] = *(const bf16x8*)(&sB[(wn + j * 16 + lr) * LDSP + kk + lq * 8]);
#pragma unroll
            for (int i = 0; i < 4; i++)
#pragma unroll
                for (int j = 0; j < 4; j++)
                    acc[i][j] = __builtin_amdgcn_mfma_f32_16x16x32_bf16(
                        fa[i], fb[j], acc[i][j], 0, 0, 0);
        }
    }

#pragma unroll
    for (int i = 0; i < 4; i++) {
        int rowb = row0 + wm + i * 16 + lq * 4;
#pragma unroll
        for (int j = 0; j < 4; j++) {
            int col = col0 + wn + j * 16 + lr;
            float bv = bias[col];
#pragma unroll
            for (int r = 0; r < 4; r++) {
                int rr = rowb + r;
                if (rr < M) {
                    float v = acc[i][j][r] + bv;
                    if (EPI == 0) {
                        v = fmaxf(v, 0.0f);
                        ((u16*)Cout)[(size_t)rr * N + col] = f2bf(v);
                    } else {
                        v += feat[(size_t)rr * N + col];
                        ((float*)Cout)[(size_t)rr * N + col] = v;
                    }
                }
            }
        }
    }
}

extern "C" void kernel_launch(void* const* d_in, const int* in_sizes, int n_in,
                              void* d_out, int out_size, void* d_ws, size_t ws_size,
                              hipStream_t stream) {
    const float* feat = (const float*)d_in[0];
    const float* W1   = (const float*)d_in[1];
    const float* b1   = (const float*)d_in[2];
    const float* W2   = (const float*)d_in[3];
    const float* b2   = (const float*)d_in[4];
    const float* eps  = (const float*)d_in[5];
    const int*   src  = (const int*)d_in[6];
    const int*   dst  = (const int*)d_in[7];
    float* out = (float*)d_out;

    char* ws = (char*)d_ws;
    float* rst_f32 = (float*)(ws);                    // 20,480,000 B
    u16*   rst_b16 = (u16*)(ws + 20480000);           // 10,240,000 B
    u16*   h_b16   = (u16*)(ws + 30720000);           // 20,480,000 B
    u16*   w1t     = (u16*)(ws + 51200000);           //  1,048,576 B
    u16*   w2t     = (u16*)(ws + 52248576);           //  1,048,576 B

    const int NE = N_NODES * D_IN;  // 5,120,000

    init_rst_k<<<NE / 4 / 256, 256, 0, stream>>>(feat, eps, rst_f32, NE);
    scatter_k<<<(N_EDGES * 128) / 256, 256, 0, stream>>>(feat, src, dst, rst_f32);
    cvt_bf16_k<<<NE / 8 / 256, 256, 0, stream>>>(rst_f32, rst_b16, NE);
    transpose_cvt_k<<<dim3(D_HID / 32, D_IN / 32), dim3(32, 8), 0, stream>>>(W1, w1t, D_IN, D_HID);
    transpose_cvt_k<<<dim3(D_IN / 32, D_HID / 32), dim3(32, 8), 0, stream>>>(W2, w2t, D_HID, D_IN);

    const int MT = (N_NODES + 127) / 128;  // 79
    gemm_k<0><<<dim3(D_HID / 128, MT), 256, 0, stream>>>(rst_b16, w1t, b1, nullptr,
                                                         (void*)h_b16, N_NODES, D_HID, D_IN);
    gemm_k<1><<<dim3(D_IN / 128, MT), 256, 0, stream>>>(h_b16, w2t, b2, feat,
                                                        (void*)out, N_NODES, D_IN, D_HID);
}

// Round 2
// 234.783 us; speedup vs baseline: 5.2202x; 5.2202x over previous
//
#include <hip/hip_runtime.h>

typedef unsigned short u16;
typedef unsigned int u32;
typedef __bf16 bf16x8 __attribute__((ext_vector_type(8)));
typedef float f32x4 __attribute__((ext_vector_type(4)));

#define N_NODES 10000
#define N_EDGES 160000
#define D_IN 512
#define D_HID 1024

__device__ __forceinline__ u16 f2bf(float f) {
    union { float f; u32 u; } v; v.f = f;
    return (u16)((v.u + 0x7fffu + ((v.u >> 16) & 1u)) >> 16);
}

// ---- CSR build: histogram of dst ----
__global__ void hist_k(const int* __restrict__ dst, int* __restrict__ counts) {
    int e = blockIdx.x * 256 + threadIdx.x;
    if (e < N_EDGES) atomicAdd(&counts[dst[e]], 1);
}

// ---- single-block exclusive scan over counts -> offsets[10001], cursor[10000] ----
#define SCAN_T 1024
#define SCAN_CH 10   // 1024*10 = 10240 >= 10000
__global__ __launch_bounds__(SCAN_T) void scan_k(const int* __restrict__ counts,
                                                 int* __restrict__ offs,
                                                 int* __restrict__ cursor) {
    __shared__ int part[SCAN_T];
    int t = threadIdx.x;
    int base = t * SCAN_CH;
    int lsum = 0;
#pragma unroll
    for (int i = 0; i < SCAN_CH; i++) {
        int idx = base + i;
        if (idx < N_NODES) lsum += counts[idx];
    }
    part[t] = lsum;
    __syncthreads();
    // Hillis-Steele inclusive scan over 1024 partials
    for (int off = 1; off < SCAN_T; off <<= 1) {
        int v = (t >= off) ? part[t - off] : 0;
        __syncthreads();
        part[t] += v;
        __syncthreads();
    }
    int run = part[t] - lsum;   // exclusive base for this chunk
#pragma unroll
    for (int i = 0; i < SCAN_CH; i++) {
        int idx = base + i;
        if (idx < N_NODES) {
            offs[idx] = run;
            cursor[idx] = run;
            run += counts[idx];
        }
    }
    if (t == SCAN_T - 1) offs[N_NODES] = part[SCAN_T - 1];
}

// ---- reorder edges into dst-sorted order ----
__global__ void reorder_k(const int* __restrict__ src, const int* __restrict__ dst,
                          int* __restrict__ cursor, int* __restrict__ ssrc) {
    int e = blockIdx.x * 256 + threadIdx.x;
    if (e >= N_EDGES) return;
    int d = dst[e];
    int pos = atomicAdd(&cursor[d], 1);
    ssrc[pos] = src[e];
}

// ---- gather-sum + (1+eps)*self, write bf16 ----
// one block of 128 threads per node; 4 floats per thread
__global__ __launch_bounds__(128) void gather_k(const float* __restrict__ feat,
                                                const float* __restrict__ eps,
                                                const int* __restrict__ offs,
                                                const int* __restrict__ ssrc,
                                                u16* __restrict__ out) {
    int n = blockIdx.x;
    int t = threadIdx.x;
    int beg = offs[n], end = offs[n + 1];
    float s = 1.0f + eps[0];
    float4 acc = *(const float4*)(feat + (size_t)n * D_IN + t * 4);
    acc.x *= s; acc.y *= s; acc.z *= s; acc.w *= s;
    int e = beg;
    // 2-deep unroll for latency overlap
    for (; e + 1 < end; e += 2) {
        int s0 = ssrc[e], s1 = ssrc[e + 1];
        float4 v0 = *(const float4*)(feat + (size_t)s0 * D_IN + t * 4);
        float4 v1 = *(const float4*)(feat + (size_t)s1 * D_IN + t * 4);
        acc.x += v0.x + v1.x; acc.y += v0.y + v1.y;
        acc.z += v0.z + v1.z; acc.w += v0.w + v1.w;
    }
    if (e < end) {
        int s0 = ssrc[e];
        float4 v0 = *(const float4*)(feat + (size_t)s0 * D_IN + t * 4);
        acc.x += v0.x; acc.y += v0.y; acc.z += v0.z; acc.w += v0.w;
    }
    uint2 o;
    o.x = (u32)f2bf(acc.x) | ((u32)f2bf(acc.y) << 16);
    o.y = (u32)f2bf(acc.z) | ((u32)f2bf(acc.w) << 16);
    *(uint2*)(out + (size_t)n * D_IN + t * 4) = o;
}

// ---- WT[n][k] = bf16(W[k][n]); W is K x N row-major ----
__global__ void transpose_cvt_k(const float* __restrict__ W, u16* __restrict__ WT,
                                int K, int N) {
    __shared__ float tile[32][33];
    int n0 = blockIdx.x * 32, k0 = blockIdx.y * 32;
    int tx = threadIdx.x, ty = threadIdx.y;
#pragma unroll
    for (int i = 0; i < 32; i += 8)
        tile[ty + i][tx] = W[(size_t)(k0 + ty + i) * N + n0 + tx];
    __syncthreads();
#pragma unroll
    for (int i = 0; i < 32; i += 8)
        WT[(size_t)(n0 + ty + i) * K + k0 + tx] = f2bf(tile[tx][ty + i]);
}

// ---- GEMM: C[M,N] = A[M,K] @ B[K,N]; A bf16 row-major, BT bf16 [N,K] ----
// 128x128 tile, BK=64, 256 threads (4 waves 2x2), 16x16x32 bf16 MFMA.
// EPI=0: C = bf16(relu(acc + bias));  EPI=1: C = acc + bias + feat (fp32)
#define LDSP 72  // 64 + 8 pad: kills 16-way bank conflict, keeps 16B align
template <int EPI>
__global__ __launch_bounds__(256) void gemm_k(const u16* __restrict__ A,
                                              const u16* __restrict__ BT,
                                              const float* __restrict__ bias,
                                              const float* __restrict__ feat,
                                              void* __restrict__ Cout,
                                              int M, int N, int K) {
    __shared__ __bf16 sA[128 * LDSP];
    __shared__ __bf16 sB[128 * LDSP];
    const int row0 = blockIdx.y * 128;
    const int col0 = blockIdx.x * 128;
    const int t = threadIdx.x;
    const int w = t >> 6, l = t & 63;
    const int wm = (w >> 1) * 64, wn = (w & 1) * 64;
    const int lr = l & 15;
    const int lq = l >> 4;

    f32x4 acc[4][4] = {};

    for (int k0 = 0; k0 < K; k0 += 64) {
        __syncthreads();
#pragma unroll
        for (int c = 0; c < 4; c++) {
            int eo = (c * 256 + t) * 8;
            int m = eo >> 6;
            int kk = eo & 63;
            int ar = row0 + m; if (ar >= M) ar = M - 1;
            *(uint4*)(&sA[m * LDSP + kk]) = *(const uint4*)(A + (size_t)ar * K + k0 + kk);
            int br = col0 + m;
            *(uint4*)(&sB[m * LDSP + kk]) = *(const uint4*)(BT + (size_t)br * K + k0 + kk);
        }
        __syncthreads();
#pragma unroll
        for (int kk = 0; kk < 64; kk += 32) {
            bf16x8 fa[4], fb[4];
#pragma unroll
            for (int i = 0; i < 4; i++)
                fa[i] = *(const bf16x8*)(&sA[(wm + i * 16 + lr) * LDSP + kk + lq * 8]);
#pragma unroll
            for (int j = 0; j < 4; j++)
                fb[j] = *(const bf16x8*)(&sB[(wn + j * 16 + lr) * LDSP + kk + lq * 8]);
#pragma unroll
            for (int i = 0; i < 4; i++)
#pragma unroll
                for (int j = 0; j < 4; j++)
                    acc[i][j] = __builtin_amdgcn_mfma_f32_16x16x32_bf16(
                        fa[i], fb[j], acc[i][j], 0, 0, 0);
        }
    }

#pragma unroll
    for (int i = 0; i < 4; i++) {
        int rowb = row0 + wm + i * 16 + lq * 4;
#pragma unroll
        for (int j = 0; j < 4; j++) {
            int col = col0 + wn + j * 16 + lr;
            float bv = bias[col];
#pragma unroll
            for (int r = 0; r < 4; r++) {
                int rr = rowb + r;
                if (rr < M) {
                    float v = acc[i][j][r] + bv;
                    if (EPI == 0) {
                        v = fmaxf(v, 0.0f);
                        ((u16*)Cout)[(size_t)rr * N + col] = f2bf(v);
                    } else {
                        v += feat[(size_t)rr * N + col];
                        ((float*)Cout)[(size_t)rr * N + col] = v;
                    }
                }
            }
        }
    }
}

extern "C" void kernel_launch(void* const* d_in, const int* in_sizes, int n_in,
                              void* d_out, int out_size, void* d_ws, size_t ws_size,
                              hipStream_t stream) {
    const float* feat = (const float*)d_in[0];
    const float* W1   = (const float*)d_in[1];
    const float* b1   = (const float*)d_in[2];
    const float* W2   = (const float*)d_in[3];
    const float* b2   = (const float*)d_in[4];
    const float* eps  = (const float*)d_in[5];
    const int*   src  = (const int*)d_in[6];
    const int*   dst  = (const int*)d_in[7];
    float* out = (float*)d_out;

    char* ws = (char*)d_ws;
    u16* rst_b16 = (u16*)(ws);                        // 10,240,000 B
    u16* h_b16   = (u16*)(ws + 10240000);             // 20,480,000 B
    u16* w1t     = (u16*)(ws + 30720000);             //  1,048,576 B
    u16* w2t     = (u16*)(ws + 31768576);             //  1,048,576 B
    int* counts  = (int*)(ws + 32817152);             //     40,000 B
    int* offs    = (int*)(ws + 32857152);             //     40,004 B
    int* cursor  = (int*)(ws + 32897160);             //     40,000 B
    int* ssrc    = (int*)(ws + 32937160);             //    640,000 B

    hipMemsetAsync(counts, 0, N_NODES * sizeof(int), stream);
    hist_k<<<(N_EDGES + 255) / 256, 256, 0, stream>>>(dst, counts);
    scan_k<<<1, SCAN_T, 0, stream>>>(counts, offs, cursor);
    reorder_k<<<(N_EDGES + 255) / 256, 256, 0, stream>>>(src, dst, cursor, ssrc);

    transpose_cvt_k<<<dim3(D_HID / 32, D_IN / 32), dim3(32, 8), 0, stream>>>(W1, w1t, D_IN, D_HID);
    transpose_cvt_k<<<dim3(D_IN / 32, D_HID / 32), dim3(32, 8), 0, stream>>>(W2, w2t, D_HID, D_IN);

    gather_k<<<N_NODES, 128, 0, stream>>>(feat, eps, offs, ssrc, rst_b16);

    const int MT = (N_NODES + 127) / 128;  // 79
    gemm_k<0><<<dim3(D_HID / 128, MT), 256, 0, stream>>>(rst_b16, w1t, b1, nullptr,
                                                         (void*)h_b16, N_NODES, D_HID, D_IN);
    gemm_k<1><<<dim3(D_IN / 128, MT), 256, 0, stream>>>(h_b16, w2t, b2, feat,
                                                        (void*)out, N_NODES, D_IN, D_HID);
}

// Round 3
// 206.892 us; speedup vs baseline: 5.9240x; 1.1348x over previous
//
#include <hip/hip_runtime.h>

typedef unsigned short u16;
typedef unsigned int u32;
typedef __bf16 bf16x8 __attribute__((ext_vector_type(8)));
typedef float f32x4 __attribute__((ext_vector_type(4)));

#define N_NODES 10000
#define N_EDGES 160000
#define D_IN 512
#define D_HID 1024

#define AS1 __attribute__((address_space(1)))
#define AS3 __attribute__((address_space(3)))

__device__ __forceinline__ u16 f2bf(float f) {
    union { float f; u32 u; } v; v.f = f;
    return (u16)((v.u + 0x7fffu + ((v.u >> 16) & 1u)) >> 16);
}
__device__ __forceinline__ float b2f(u32 h) {
    union { u32 u; float f; } v; v.u = h << 16; return v.f;
}

// ---- CSR build: histogram of dst ----
__global__ void hist_k(const int* __restrict__ dst, int* __restrict__ counts) {
    int e = blockIdx.x * 256 + threadIdx.x;
    if (e < N_EDGES) atomicAdd(&counts[dst[e]], 1);
}

// ---- single-block scan via wave shuffles: offs[10001], cursor[10000] ----
__global__ __launch_bounds__(1024) void scan_k(const int* __restrict__ counts,
                                               int* __restrict__ offs,
                                               int* __restrict__ cursor) {
    __shared__ int wpre[16];
    int t = threadIdx.x, l = t & 63, w = t >> 6;
    int base = t * 10;
    int c[10];
    int lsum = 0;
#pragma unroll
    for (int i = 0; i < 10; i++) {
        int idx = base + i;
        c[i] = (idx < N_NODES) ? counts[idx] : 0;
        lsum += c[i];
    }
    // wave-inclusive scan of lsum
    int sc = lsum;
#pragma unroll
    for (int d = 1; d < 64; d <<= 1) {
        int v = __shfl_up(sc, d);
        if (l >= d) sc += v;
    }
    __shared__ int wsum[16];
    if (l == 63) wsum[w] = sc;
    __syncthreads();
    if (w == 0 && l < 16) {
        int v = wsum[l];
        int p = v;
#pragma unroll
        for (int d = 1; d < 16; d <<= 1) {
            int u = __shfl_up(p, d);
            if (l >= d) p += u;
        }
        wpre[l] = p - v;
    }
    __syncthreads();
    int run = wpre[w] + sc - lsum;   // exclusive prefix for this thread's chunk
#pragma unroll
    for (int i = 0; i < 10; i++) {
        int idx = base + i;
        if (idx < N_NODES) { offs[idx] = run; cursor[idx] = run; run += c[i]; }
    }
    if (t == 1023) offs[N_NODES] = wpre[15] + sc;
}

// ---- reorder edges into dst-sorted order ----
__global__ void reorder_k(const int* __restrict__ src, const int* __restrict__ dst,
                          int* __restrict__ cursor, int* __restrict__ ssrc) {
    int e = blockIdx.x * 256 + threadIdx.x;
    if (e >= N_EDGES) return;
    int d = dst[e];
    int pos = atomicAdd(&cursor[d], 1);
    ssrc[pos] = src[e];
}

// ---- fp32 -> bf16 convert (feat copy), 8 elems/thread ----
__global__ void cvt_bf16_k(const float* __restrict__ in, u16* __restrict__ out, int n) {
    int i = (blockIdx.x * 256 + threadIdx.x) * 8;
    if (i >= n) return;
    float4 a = *(const float4*)(in + i);
    float4 b = *(const float4*)(in + i + 4);
    uint4 o;
    o.x = (u32)f2bf(a.x) | ((u32)f2bf(a.y) << 16);
    o.y = (u32)f2bf(a.z) | ((u32)f2bf(a.w) << 16);
    o.z = (u32)f2bf(b.x) | ((u32)f2bf(b.y) << 16);
    o.w = (u32)f2bf(b.z) | ((u32)f2bf(b.w) << 16);
    *(uint4*)(out + i) = o;
}

// ---- fused W1/W2 transpose+convert: WT[n][k] = bf16(W[k][n]) ----
__global__ void transw_k(const float* __restrict__ W1, u16* __restrict__ w1t,
                         const float* __restrict__ W2, u16* __restrict__ w2t) {
    __shared__ float tile[32][33];
    int b = blockIdx.x;
    const float* W; u16* WT; int K, N, nt;
    if (b < 512) { W = W1; WT = w1t; K = D_IN;  N = D_HID; nt = 32; }
    else         { b -= 512; W = W2; WT = w2t; K = D_HID; N = D_IN;  nt = 16; }
    int n0 = (b % nt) * 32, k0 = (b / nt) * 32;
    int tx = threadIdx.x, ty = threadIdx.y;
#pragma unroll
    for (int i = 0; i < 32; i += 8)
        tile[ty + i][tx] = W[(size_t)(k0 + ty + i) * N + n0 + tx];
    __syncthreads();
#pragma unroll
    for (int i = 0; i < 32; i += 8)
        WT[(size_t)(n0 + ty + i) * K + k0 + tx] = f2bf(tile[tx][ty + i]);
}

// ---- gather-sum from bf16 feat + (1+eps)*fp32 self, write bf16 ----
// one wave (64 lanes) per node, 8 bf16 per lane
__global__ __launch_bounds__(128) void gather_k(const float* __restrict__ feat,
                                                const u16* __restrict__ featb,
                                                const float* __restrict__ eps,
                                                const int* __restrict__ offs,
                                                const int* __restrict__ ssrc,
                                                u16* __restrict__ out) {
    int n = (blockIdx.x * 128 + threadIdx.x) >> 6;
    int l = threadIdx.x & 63;
    if (n >= N_NODES) return;
    int beg = offs[n], end = offs[n + 1];
    float s = 1.0f + eps[0];
    float4 s0 = *(const float4*)(feat + (size_t)n * D_IN + l * 8);
    float4 s1 = *(const float4*)(feat + (size_t)n * D_IN + l * 8 + 4);
    float acc[8] = { s * s0.x, s * s0.y, s * s0.z, s * s0.w,
                     s * s1.x, s * s1.y, s * s1.z, s * s1.w };
    int e = beg;
    for (; e + 4 <= end; e += 4) {
        int i0 = ssrc[e], i1 = ssrc[e + 1], i2 = ssrc[e + 2], i3 = ssrc[e + 3];
        uint4 v0 = *(const uint4*)(featb + (size_t)i0 * D_IN + l * 8);
        uint4 v1 = *(const uint4*)(featb + (size_t)i1 * D_IN + l * 8);
        uint4 v2 = *(const uint4*)(featb + (size_t)i2 * D_IN + l * 8);
        uint4 v3 = *(const uint4*)(featb + (size_t)i3 * D_IN + l * 8);
#define ACC4(v) \
        acc[0] += b2f(v.x & 0xffffu); acc[1] += b2f(v.x >> 16); \
        acc[2] += b2f(v.y & 0xffffu); acc[3] += b2f(v.y >> 16); \
        acc[4] += b2f(v.z & 0xffffu); acc[5] += b2f(v.z >> 16); \
        acc[6] += b2f(v.w & 0xffffu); acc[7] += b2f(v.w >> 16);
        ACC4(v0) ACC4(v1) ACC4(v2) ACC4(v3)
    }
    for (; e < end; e++) {
        int i0 = ssrc[e];
        uint4 v0 = *(const uint4*)(featb + (size_t)i0 * D_IN + l * 8);
        ACC4(v0)
    }
#undef ACC4
    uint4 o;
    o.x = (u32)f2bf(acc[0]) | ((u32)f2bf(acc[1]) << 16);
    o.y = (u32)f2bf(acc[2]) | ((u32)f2bf(acc[3]) << 16);
    o.z = (u32)f2bf(acc[4]) | ((u32)f2bf(acc[5]) << 16);
    o.w = (u32)f2bf(acc[6]) | ((u32)f2bf(acc[7]) << 16);
    *(uint4*)(out + (size_t)n * D_IN + l * 8) = o;
}

// ---- GEMM: C[M,N] = A[M,K] @ B[K,N]; A bf16 row-major, BT bf16 [N,K] ----
// 128x128 tile, BK=64, 256 thr (4 waves 2x2), 16x16x32 bf16 MFMA.
// global_load_lds width-16 staging; XOR chunk swizzle (slot c holds global
// chunk c^(row&7)) applied on the GLOBAL side so the wave-uniform LDS dest
// constraint is satisfied; fragment reads then spread over all 32 banks.
// EPI=0: C = bf16(relu(acc + bias));  EPI=1: C = acc + bias + feat (fp32)
template <int EPI>
__global__ __launch_bounds__(256) void gemm_k(const u16* __restrict__ A,
                                              const u16* __restrict__ BT,
                                              const float* __restrict__ bias,
                                              const float* __restrict__ feat,
                                              void* __restrict__ Cout,
                                              int M, int N, int K) {
    __shared__ __bf16 sA[128 * 64];
    __shared__ __bf16 sB[128 * 64];
    const int row0 = blockIdx.y * 128;
    const int col0 = blockIdx.x * 128;
    const int t = threadIdx.x;
    const int w = t >> 6, l = t & 63;
    const int wm = (w >> 1) * 64, wn = (w & 1) * 64;
    const int lr = l & 15;
    const int lq = l >> 4;

    // staging setup: wave w covers tile rows w*32..w*32+31 (4 segs of 8 rows)
    const u16* pA[4];
    const u16* pB[4];
    __bf16* lA[4];
    __bf16* lB[4];
    {
        int rloc = w * 32 + (l >> 3);
        int gch8 = (((l & 7) ^ (l >> 3)) * 8);   // swizzled global k-chunk
#pragma unroll
        for (int q = 0; q < 4; q++) {
            int ar = row0 + rloc + q * 8; if (ar > M - 1) ar = M - 1;
            pA[q] = A + (size_t)ar * K + gch8;
            int br = col0 + rloc + q * 8;
            pB[q] = BT + (size_t)br * K + gch8;
            lA[q] = sA + (w * 32 + q * 8) * 64;   // wave-uniform
            lB[q] = sB + (w * 32 + q * 8) * 64;
        }
    }
    // fragment-read swizzle: slot elem-offset for global chunk (lq + kk/8)
    const int fo = ((lq ^ (lr & 7)) * 8);

    f32x4 acc[4][4] = {};

    for (int k0 = 0; k0 < K; k0 += 64) {
        __syncthreads();
#pragma unroll
        for (int q = 0; q < 4; q++) {
            __builtin_amdgcn_global_load_lds((const AS1 void*)(pA[q] + k0),
                                             (AS3 void*)lA[q], 16, 0, 0);
            __builtin_amdgcn_global_load_lds((const AS1 void*)(pB[q] + k0),
                                             (AS3 void*)lB[q], 16, 0, 0);
        }
        __syncthreads();
#pragma unroll
        for (int kk = 0; kk < 64; kk += 32) {
            const int fx = fo ^ kk;   // kk=32 flips chunk bit 2 (elem bit 5)
            bf16x8 fa[4], fb[4];
#pragma unroll
            for (int i = 0; i < 4; i++)
                fa[i] = *(const bf16x8*)(sA + (wm + i * 16 + lr) * 64 + fx);
#pragma unroll
            for (int j = 0; j < 4; j++)
                fb[j] = *(const bf16x8*)(sB + (wn + j * 16 + lr) * 64 + fx);
#pragma unroll
            for (int i = 0; i < 4; i++)
#pragma unroll
                for (int j = 0; j < 4; j++)
                    acc[i][j] = __builtin_amdgcn_mfma_f32_16x16x32_bf16(
                        fa[i], fb[j], acc[i][j], 0, 0, 0);
        }
    }

#pragma unroll
    for (int i = 0; i < 4; i++) {
        int rowb = row0 + wm + i * 16 + lq * 4;
#pragma unroll
        for (int j = 0; j < 4; j++) {
            int col = col0 + wn + j * 16 + lr;
            float bv = bias[col];
#pragma unroll
            for (int r = 0; r < 4; r++) {
                int rr = rowb + r;
                if (rr < M) {
                    float v = acc[i][j][r] + bv;
                    if (EPI == 0) {
                        v = fmaxf(v, 0.0f);
                        ((u16*)Cout)[(size_t)rr * N + col] = f2bf(v);
                    } else {
                        v += feat[(size_t)rr * N + col];
                        ((float*)Cout)[(size_t)rr * N + col] = v;
                    }
                }
            }
        }
    }
}

extern "C" void kernel_launch(void* const* d_in, const int* in_sizes, int n_in,
                              void* d_out, int out_size, void* d_ws, size_t ws_size,
                              hipStream_t stream) {
    const float* feat = (const float*)d_in[0];
    const float* W1   = (const float*)d_in[1];
    const float* b1   = (const float*)d_in[2];
    const float* W2   = (const float*)d_in[3];
    const float* b2   = (const float*)d_in[4];
    const float* eps  = (const float*)d_in[5];
    const int*   src  = (const int*)d_in[6];
    const int*   dst  = (const int*)d_in[7];
    float* out = (float*)d_out;

    char* ws = (char*)d_ws;
    u16* rst_b16 = (u16*)(ws);                        // 10,240,000 B
    u16* h_b16   = (u16*)(ws + 10240000);             // 20,480,000 B
    u16* featb   = (u16*)(ws + 30720000);             // 10,240,000 B
    u16* w1t     = (u16*)(ws + 40960000);             //  1,048,576 B
    u16* w2t     = (u16*)(ws + 42008576);             //  1,048,576 B
    int* counts  = (int*)(ws + 43057152);             //     40,000 B
    int* offs    = (int*)(ws + 43097152);             //     40,004 B
    int* cursor  = (int*)(ws + 43137160);             //     40,000 B
    int* ssrc    = (int*)(ws + 43177160);             //    640,000 B

    const int NE = N_NODES * D_IN;  // 5,120,000

    hipMemsetAsync(counts, 0, N_NODES * sizeof(int), stream);
    hist_k<<<(N_EDGES + 255) / 256, 256, 0, stream>>>(dst, counts);
    scan_k<<<1, 1024, 0, stream>>>(counts, offs, cursor);
    reorder_k<<<(N_EDGES + 255) / 256, 256, 0, stream>>>(src, dst, cursor, ssrc);

    cvt_bf16_k<<<NE / 8 / 256, 256, 0, stream>>>(feat, featb, NE);
    transw_k<<<1024, dim3(32, 8), 0, stream>>>(W1, w1t, W2, w2t);

    gather_k<<<(N_NODES + 1) / 2, 128, 0, stream>>>(feat, featb, eps, offs, ssrc, rst_b16);

    const int MT = (N_NODES + 127) / 128;  // 79
    gemm_k<0><<<dim3(D_HID / 128, MT), 256, 0, stream>>>(rst_b16, w1t, b1, nullptr,
                                                         (void*)h_b16, N_NODES, D_HID, D_IN);
    gemm_k<1><<<dim3(D_IN / 128, MT), 256, 0, stream>>>(h_b16, w2t, b2, feat,
                                                        (void*)out, N_NODES, D_IN, D_HID);
}